// Round 3
// baseline (1091.174 us; speedup 1.0000x reference)
//
#include <hip/hip_runtime.h>

#define NN 20000
#define NE 400000

typedef __attribute__((ext_vector_type(8))) short bf8;
typedef __attribute__((ext_vector_type(4))) float f32x4;

__device__ __forceinline__ float sigf(float x) { return 1.0f / (1.0f + __expf(-x)); }
__device__ __forceinline__ short bfc(float f) {
    __bf16 h = (__bf16)f;                // RNE hardware convert
    return __builtin_bit_cast(short, h);
}

// ---------- weight prep: transpose + bf16 + fold norms: dst[w][K] = sc * src[K][w] ----------
__global__ void prep_kernel(const float* __restrict__ s1, const float* __restrict__ s2,
                            int K1, int Kt, int Nw, float sc1, float sc2,
                            unsigned short* __restrict__ dst, int total)
{
    int idx = blockIdx.x * 256 + threadIdx.x;
    if (idx >= total) return;
    int w = idx / Kt, K = idx - w * Kt;
    float v = (K < K1) ? s1[(size_t)K * Nw + w] * sc1
                       : s2[(size_t)(K - K1) * Nw + w] * sc2;
    dst[idx] = (unsigned short)bfc(v);
}

// =============== message kernel: 32 edges/block, shared-z MFMA TP + gate + scatter ===============
__global__ __launch_bounds__(256, 2)
void msg_kernel(const float* __restrict__ nf, const float* __restrict__ ea,
                const int* __restrict__ eidx,
                const unsigned short* __restrict__ wA,   // [96][768] bf16, norms folded
                const unsigned short* __restrict__ wB,   // [32][768] bf16, norms folded
                float* __restrict__ agg)
{
    const int e0   = blockIdx.x * 32;
    const int t    = threadIdx.x;
    const int wid  = t >> 6;
    const int lane = t & 63;
    const int ln   = lane & 15;
    const int okt  = lane >> 4;

    __shared__ float s_xs[32][65];
    __shared__ float s_xv[32][97];      // [e][u*3+k]
    __shared__ float s_es[32][8];
    __shared__ float s_evT[32][3][8];   // [e][k][v]
    __shared__ float s_gate[32][33];    // sigmoid gates, w-64
    __shared__ __align__(16) unsigned short z_A[32][136];   // chunk of z_A (K=128)
    __shared__ __align__(16) unsigned short z_B[96][136];   // chunk of z_B (rows (k,e))
    __shared__ int s_row[32], s_col[32];

    if (t < 32) s_row[t] = eidx[e0 + t];
    else if (t < 64) s_col[t - 32] = eidx[NE + e0 + (t - 32)];
    for (int i = t; i < 32 * 32; i += 256) {
        int e = i >> 5, c = i & 31;
        float v = ea[(size_t)(e0 + e) * 32 + c];
        if (c < 8) s_es[e][c] = v;
        else { int d = c - 8; s_evT[e][d % 3][d / 3] = v; }
    }
    __syncthreads();
    for (int i = t; i < 32 * 40; i += 256) {
        int e = i / 40, q = i - e * 40;
        f32x4 f4 = *((const f32x4*)nf + (size_t)s_col[e] * 40 + q);
        if (q < 16) {
            #pragma unroll
            for (int j = 0; j < 4; ++j) s_xs[e][q * 4 + j] = f4[j];
        } else {
            #pragma unroll
            for (int j = 0; j < 4; ++j) s_xv[e][(q - 16) * 4 + j] = f4[j];
        }
    }

    f32x4 acc[6] = {};
    const unsigned short* wAp = wA + (size_t)(wid * 48 + ln) * 768;          // wid<2
    const unsigned short* wBp = wB + (size_t)ln * 768;                       // wid>=2

    for (int ch = 0; ch < 6; ++ch) {
        __syncthreads();   // prev chunk's MFMA reads done (or prologue done)
        // ---- build z_A chunk: 512 octets ----
        #pragma unroll
        for (int r = 0; r < 2; ++r) {
            int o = t + r * 256;
            int row = o >> 4, c8 = o & 15;
            int Kc = ch * 128 + c8 * 8;
            f32x4 lo, hi;
            if (Kc < 512) {                       // z_ss: xs[u]*es[v]
                float x = s_xs[row][Kc >> 3];
                lo = x * *(const f32x4*)&s_es[row][0];
                hi = x * *(const f32x4*)&s_es[row][4];
            } else {                              // dd: sum_k xv[u][k]*ev[v][k]
                int u = (Kc - 512) >> 3;
                float x0 = s_xv[row][u * 3], x1 = s_xv[row][u * 3 + 1], x2 = s_xv[row][u * 3 + 2];
                lo = x0 * *(const f32x4*)&s_evT[row][0][0] + x1 * *(const f32x4*)&s_evT[row][1][0]
                   + x2 * *(const f32x4*)&s_evT[row][2][0];
                hi = x0 * *(const f32x4*)&s_evT[row][0][4] + x1 * *(const f32x4*)&s_evT[row][1][4]
                   + x2 * *(const f32x4*)&s_evT[row][2][4];
            }
            bf8 pk;
            #pragma unroll
            for (int j = 0; j < 4; ++j) { pk[j] = bfc(lo[j]); pk[j + 4] = bfc(hi[j]); }
            *(bf8*)&z_A[row][c8 * 8] = pk;
        }
        // ---- build z_B chunk: 1536 octets, rows R=(k*32+e) ----
        #pragma unroll
        for (int r = 0; r < 6; ++r) {
            int o = t + r * 256;
            int R = o >> 4, c8 = o & 15;
            int k = R >> 5, e = R & 31;
            int Kc = ch * 128 + c8 * 8;
            f32x4 lo, hi;
            if (Kc < 512) {                       // sv: xs[u]*ev[v][k]
                float x = s_xs[e][Kc >> 3];
                lo = x * *(const f32x4*)&s_evT[e][k][0];
                hi = x * *(const f32x4*)&s_evT[e][k][4];
            } else {                              // vs: xv[u][k]*es[v]
                float x = s_xv[e][((Kc - 512) >> 3) * 3 + k];
                lo = x * *(const f32x4*)&s_es[e][0];
                hi = x * *(const f32x4*)&s_es[e][4];
            }
            bf8 pk;
            #pragma unroll
            for (int j = 0; j < 4; ++j) { pk[j] = bfc(lo[j]); pk[j + 4] = bfc(hi[j]); }
            *(bf8*)&z_B[R][c8 * 8] = pk;
        }
        __syncthreads();   // builds visible
        // ---- MFMA from LDS ----
        if (wid < 2) {
            // GEMM A: hs[32 x 96], this wave: N cols wid*48 .. wid*48+47
            #pragma unroll
            for (int ks = 0; ks < 4; ++ks) {
                int ko = ks * 32 + okt * 8;
                bf8 a0 = *(const bf8*)&z_A[ln][ko];
                bf8 a1 = *(const bf8*)&z_A[16 + ln][ko];
                const unsigned short* wp = wAp + ch * 128 + ko;
                bf8 b0 = *(const bf8*)(wp);
                bf8 b1 = *(const bf8*)(wp + 16 * 768);
                bf8 b2 = *(const bf8*)(wp + 32 * 768);
                acc[0] = __builtin_amdgcn_mfma_f32_16x16x32_bf16(a0, b0, acc[0], 0, 0, 0);
                acc[1] = __builtin_amdgcn_mfma_f32_16x16x32_bf16(a0, b1, acc[1], 0, 0, 0);
                acc[2] = __builtin_amdgcn_mfma_f32_16x16x32_bf16(a0, b2, acc[2], 0, 0, 0);
                acc[3] = __builtin_amdgcn_mfma_f32_16x16x32_bf16(a1, b0, acc[3], 0, 0, 0);
                acc[4] = __builtin_amdgcn_mfma_f32_16x16x32_bf16(a1, b1, acc[4], 0, 0, 0);
                acc[5] = __builtin_amdgcn_mfma_f32_16x16x32_bf16(a1, b2, acc[5], 0, 0, 0);
            }
        } else {
            // GEMM B: hv[(k,e)=96 x 32], this wave: M rows (wid-2)*48 .. +47, all 32 cols
            int mb = (wid - 2) * 48;
            #pragma unroll
            for (int ks = 0; ks < 4; ++ks) {
                int ko = ks * 32 + okt * 8;
                bf8 a0 = *(const bf8*)&z_B[mb + ln][ko];
                bf8 a1 = *(const bf8*)&z_B[mb + 16 + ln][ko];
                bf8 a2 = *(const bf8*)&z_B[mb + 32 + ln][ko];
                const unsigned short* wp = wBp + ch * 128 + ko;
                bf8 b0 = *(const bf8*)(wp);
                bf8 b1 = *(const bf8*)(wp + 16 * 768);
                acc[0] = __builtin_amdgcn_mfma_f32_16x16x32_bf16(a0, b0, acc[0], 0, 0, 0);
                acc[1] = __builtin_amdgcn_mfma_f32_16x16x32_bf16(a0, b1, acc[1], 0, 0, 0);
                acc[2] = __builtin_amdgcn_mfma_f32_16x16x32_bf16(a1, b0, acc[2], 0, 0, 0);
                acc[3] = __builtin_amdgcn_mfma_f32_16x16x32_bf16(a1, b1, acc[3], 0, 0, 0);
                acc[4] = __builtin_amdgcn_mfma_f32_16x16x32_bf16(a2, b0, acc[4], 0, 0, 0);
                acc[5] = __builtin_amdgcn_mfma_f32_16x16x32_bf16(a2, b1, acc[5], 0, 0, 0);
            }
        }
    }

    // ---- epilogue: gate + scatter ----
    if (wid == 0) {
        // cols 0..47: all scalar outputs -> silu + atomic, straight from regs
        #pragma unroll
        for (int m2 = 0; m2 < 2; ++m2)
            #pragma unroll
            for (int j = 0; j < 3; ++j)
                #pragma unroll
                for (int r = 0; r < 4; ++r) {
                    int e = m2 * 16 + okt * 4 + r;
                    float h = acc[m2 * 3 + j][r];
                    atomicAdd(agg + (size_t)s_row[e] * 160 + j * 16 + ln, h * sigf(h));
                }
    } else if (wid == 1) {
        #pragma unroll
        for (int m2 = 0; m2 < 2; ++m2)
            #pragma unroll
            for (int r = 0; r < 4; ++r) {
                int e = m2 * 16 + okt * 4 + r;
                float h = acc[m2 * 3][r];         // j=0: w = 48+ln (scalar)
                atomicAdd(agg + (size_t)s_row[e] * 160 + 48 + ln, h * sigf(h));
                s_gate[e][ln]      = sigf(acc[m2 * 3 + 1][r]);   // w = 64+ln
                s_gate[e][16 + ln] = sigf(acc[m2 * 3 + 2][r]);   // w = 80+ln
            }
    }
    __syncthreads();
    if (wid >= 2) {
        #pragma unroll
        for (int m = 0; m < 3; ++m)
            #pragma unroll
            for (int tt = 0; tt < 2; ++tt)
                #pragma unroll
                for (int r = 0; r < 4; ++r) {
                    int R = (wid - 2) * 48 + m * 16 + okt * 4 + r;
                    int k = R >> 5, e = R & 31;
                    int w2 = tt * 16 + ln;
                    float val = acc[m * 2 + tt][r] * s_gate[e][w2];
                    atomicAdd(agg + (size_t)s_row[e] * 160 + 64 + w2 * 3 + k, val);
                }
    }
}

// =============== update kernel: 16 nodes/block, folded agglin + shared-z MFMA + linear + residual ===============
__global__ __launch_bounds__(256, 2)
void upd_kernel(const float* __restrict__ nf, const float* __restrict__ agg,
                const unsigned short* __restrict__ wA,   // [96][7168]
                const unsigned short* __restrict__ wB,   // [32][5120]
                const float* __restrict__ Wlms, const float* __restrict__ Wlmv,
                const float* __restrict__ Wls, const float* __restrict__ Wlv,
                float* __restrict__ out)
{
    const int n0   = blockIdx.x * 16;
    const int t    = threadIdx.x;
    const int wid  = t >> 6;
    const int lane = t & 63;
    const int ln   = lane & 15;
    const int okt  = lane >> 4;

    __shared__ float s_xs[16][65];
    __shared__ float s_xv[16][97];
    __shared__ float s_as[16][100];     // ags (post agglin)
    __shared__ float s_avT[16][3][36];  // agv transposed [n][k][v]
    __shared__ float s_gate[16][33];
    __shared__ float s_gs2[16][65];
    __shared__ float s_gv2[16][97];
    __shared__ __align__(16) unsigned short z_A[16][264];  // chunk K=256
    __shared__ __align__(16) unsigned short z_B[48][264];  // rows (k*16+n)

    float* s_ag = (float*)&z_B[0][0];   // [16*160] temp alias (prologue only)

    for (int i = t; i < 16 * 40; i += 256) {
        int n = i / 40, q = i - n * 40;
        f32x4 f4 = *((const f32x4*)nf + (size_t)(n0 + n) * 40 + q);
        if (q < 16) {
            #pragma unroll
            for (int j = 0; j < 4; ++j) s_xs[n][q * 4 + j] = f4[j];
        } else {
            #pragma unroll
            for (int j = 0; j < 4; ++j) s_xv[n][(q - 16) * 4 + j] = f4[j];
        }
    }
    for (int i = t; i < 16 * 160; i += 256)
        s_ag[i] = agg[(size_t)n0 * 160 + i];
    __syncthreads();

    // folded agglin: ags[n][w] and avT[n][k][v]
    #pragma unroll
    for (int r = 0; r < 6; ++r) {
        int o = t + r * 256;
        int n = o / 96, q = o - n * 96;
        float a = 0.f;
        #pragma unroll
        for (int u = 0; u < 64; ++u) a = fmaf(s_ag[n * 160 + u], Wlms[u * 96 + q], a);
        s_as[n][q] = a * 0.125f;
    }
    #pragma unroll
    for (int r = 0; r < 6; ++r) {
        int o = t + r * 256;
        int n = o / 96, q = o - n * 96, k = q >> 5, v = q & 31;
        float a = 0.f;
        #pragma unroll
        for (int u = 0; u < 32; ++u) a = fmaf(s_ag[n * 160 + 64 + u * 3 + k], Wlmv[u * 32 + v], a);
        s_avT[n][k][v] = a * 0.17677669529663687f;
    }

    f32x4 acc[3] = {};
    const unsigned short* wAp = wA + (size_t)(wid * 48 + ln) * 7168;          // wid<2
    const unsigned short* wBp = wB + (size_t)((wid - 2) * 16 + ln) * 5120;    // wid>=2

    for (int ch = 0; ch < 28; ++ch) {
        __syncthreads();   // prev MFMA reads done / prologue done
        // ---- build z_A chunk: 512 octets ----
        #pragma unroll
        for (int r = 0; r < 2; ++r) {
            int o = t + r * 256;
            int row = o >> 5, c8 = o & 31;
            int Kc = ch * 256 + c8 * 8;
            f32x4 lo, hi;
            if (Kc < 6144) {                      // ss: xs[u]*ags[v], col = u*96+v
                int u = Kc / 96, v0 = Kc - u * 96;
                float x = s_xs[row][u];
                lo = x * *(const f32x4*)&s_as[row][v0];
                hi = x * *(const f32x4*)&s_as[row][v0 + 4];
            } else {                              // vv: sum_k xv[u][k]*agv[v][k]
                int Kp = Kc - 6144;
                int u = Kp >> 5, v0 = Kp & 31;
                float x0 = s_xv[row][u * 3], x1 = s_xv[row][u * 3 + 1], x2 = s_xv[row][u * 3 + 2];
                lo = x0 * *(const f32x4*)&s_avT[row][0][v0] + x1 * *(const f32x4*)&s_avT[row][1][v0]
                   + x2 * *(const f32x4*)&s_avT[row][2][v0];
                hi = x0 * *(const f32x4*)&s_avT[row][0][v0 + 4] + x1 * *(const f32x4*)&s_avT[row][1][v0 + 4]
                   + x2 * *(const f32x4*)&s_avT[row][2][v0 + 4];
            }
            bf8 pk;
            #pragma unroll
            for (int j = 0; j < 4; ++j) { pk[j] = bfc(lo[j]); pk[j + 4] = bfc(hi[j]); }
            *(bf8*)&z_A[row][c8 * 8] = pk;
        }
        // ---- build z_B chunk (only 20 chunks of K=5120): 1536 octets ----
        if (ch < 20) {
            #pragma unroll
            for (int r = 0; r < 6; ++r) {
                int o = t + r * 256;
                int R = o >> 5, c8 = o & 31;
                int k = R >> 4, n = R & 15;
                int Kc = ch * 256 + c8 * 8;
                f32x4 lo, hi;
                if (Kc < 2048) {                  // sv: xs[u]*agv[v][k], col = u*32+v
                    int u = Kc >> 5, v0 = Kc & 31;
                    float x = s_xs[n][u];
                    lo = x * *(const f32x4*)&s_avT[n][k][v0];
                    hi = x * *(const f32x4*)&s_avT[n][k][v0 + 4];
                } else {                          // vs: xv[u][k]*ags[v], col = u*96+v
                    int Kp = Kc - 2048;
                    int u = Kp / 96, v0 = Kp - u * 96;
                    float x = s_xv[n][u * 3 + k];
                    lo = x * *(const f32x4*)&s_as[n][v0];
                    hi = x * *(const f32x4*)&s_as[n][v0 + 4];
                }
                bf8 pk;
                #pragma unroll
                for (int j = 0; j < 4; ++j) { pk[j] = bfc(lo[j]); pk[j + 4] = bfc(hi[j]); }
                *(bf8*)&z_B[R][c8 * 8] = pk;
            }
        }
        __syncthreads();
        // ---- MFMA ----
        if (wid < 2) {
            #pragma unroll
            for (int ks = 0; ks < 8; ++ks) {
                int ko = ks * 32 + okt * 8;
                bf8 a = *(const bf8*)&z_A[ln][ko];
                const unsigned short* wp = wAp + ch * 256 + ko;
                bf8 b0 = *(const bf8*)(wp);
                bf8 b1 = *(const bf8*)(wp + 16 * 7168);
                bf8 b2 = *(const bf8*)(wp + 32 * 7168);
                acc[0] = __builtin_amdgcn_mfma_f32_16x16x32_bf16(a, b0, acc[0], 0, 0, 0);
                acc[1] = __builtin_amdgcn_mfma_f32_16x16x32_bf16(a, b1, acc[1], 0, 0, 0);
                acc[2] = __builtin_amdgcn_mfma_f32_16x16x32_bf16(a, b2, acc[2], 0, 0, 0);
            }
        } else if (ch < 20) {
            #pragma unroll
            for (int ks = 0; ks < 8; ++ks) {
                int ko = ks * 32 + okt * 8;
                bf8 a0 = *(const bf8*)&z_B[ln][ko];
                bf8 a1 = *(const bf8*)&z_B[16 + ln][ko];
                bf8 a2 = *(const bf8*)&z_B[32 + ln][ko];
                bf8 b = *(const bf8*)(wBp + ch * 256 + ko);
                acc[0] = __builtin_amdgcn_mfma_f32_16x16x32_bf16(a0, b, acc[0], 0, 0, 0);
                acc[1] = __builtin_amdgcn_mfma_f32_16x16x32_bf16(a1, b, acc[1], 0, 0, 0);
                acc[2] = __builtin_amdgcn_mfma_f32_16x16x32_bf16(a2, b, acc[2], 0, 0, 0);
            }
        }
    }

    // ---- epilogue ----
    if (wid < 2) {
        #pragma unroll
        for (int j = 0; j < 3; ++j)
            #pragma unroll
            for (int r = 0; r < 4; ++r) {
                int n = okt * 4 + r, w = wid * 48 + j * 16 + ln;
                float h = acc[j][r];
                if (w < 64) s_gs2[n][w] = h * sigf(h);
                else        s_gate[n][w - 64] = sigf(h);
            }
    }
    __syncthreads();
    if (wid >= 2) {
        #pragma unroll
        for (int m = 0; m < 3; ++m)
            #pragma unroll
            for (int r = 0; r < 4; ++r) {
                int R = m * 16 + okt * 4 + r;
                int k = R >> 4, n = R & 15;
                int w2 = (wid - 2) * 16 + ln;
                s_gv2[n][w2 * 3 + k] = acc[m][r] * s_gate[n][w2];
            }
    }
    __syncthreads();
    // final irrep linear + residual
    for (int i = t; i < 16 * 64; i += 256) {
        int n = i >> 6, w = i & 63;
        float a = 0.f;
        #pragma unroll
        for (int u = 0; u < 64; ++u) a = fmaf(s_gs2[n][u], Wls[u * 64 + w], a);
        size_t o = (size_t)(n0 + n) * 160 + w;
        out[o] = nf[o] + a * 0.125f;
    }
    for (int i = t; i < 16 * 96; i += 256) {
        int n = i / 96, wk = i - n * 96, w = wk / 3, k = wk - w * 3;
        float a = 0.f;
        #pragma unroll
        for (int u = 0; u < 32; ++u) a = fmaf(s_gv2[n][u * 3 + k], Wlv[u * 32 + w], a);
        size_t o = (size_t)(n0 + n) * 160 + 64 + wk;
        out[o] = nf[o] + a * 0.17677669529663687f;
    }
}

extern "C" void kernel_launch(void* const* d_in, const int* in_sizes, int n_in,
                              void* d_out, int out_size, void* d_ws, size_t ws_size,
                              hipStream_t stream) {
    const float* nf   = (const float*)d_in[0];
    const float* ea   = (const float*)d_in[1];
    const int*   eidx = (const int*)d_in[3];
    const float* Wmss = (const float*)d_in[4];
    const float* Wmvv = (const float*)d_in[5];
    const float* Wmsv = (const float*)d_in[6];
    const float* Wmvs = (const float*)d_in[7];
    const float* Wlms = (const float*)d_in[8];
    const float* Wlmv = (const float*)d_in[9];
    const float* Wuss = (const float*)d_in[10];
    const float* Wuvv = (const float*)d_in[11];
    const float* Wusv = (const float*)d_in[12];
    const float* Wuvs = (const float*)d_in[13];
    const float* Wlus = (const float*)d_in[14];
    const float* Wluv = (const float*)d_in[15];
    float* out = (float*)d_out;

    float* agg = (float*)d_ws;                          // [NN,160]
    unsigned short* wAm = (unsigned short*)(agg + (size_t)NN * 160);
    unsigned short* wBm = wAm + 96 * 768;
    unsigned short* wAu = wBm + 32 * 768;
    unsigned short* wBu = wAu + (size_t)96 * 7168;

    const float NSM = 0.03608439182435161f;   // 1/sqrt(768)
    const float NSU = 0.011811365506297619f;  // 1/sqrt(7168)
    const float NVU = 0.013975424859373686f;  // 1/sqrt(5120)
    const float S3  = 0.57735026918962576f;   // 1/sqrt(3)

    prep_kernel<<<(96 * 768 + 255) / 256, 256, 0, stream>>>(Wmss, Wmvv, 512, 768, 96, NSM, NSM * S3, wAm, 96 * 768);
    prep_kernel<<<(32 * 768 + 255) / 256, 256, 0, stream>>>(Wmsv, Wmvs, 512, 768, 32, NSM, NSM, wBm, 32 * 768);
    prep_kernel<<<(96 * 7168 + 255) / 256, 256, 0, stream>>>(Wuss, Wuvv, 6144, 7168, 96, NSU, NSU * S3, wAu, 96 * 7168);
    prep_kernel<<<(32 * 5120 + 255) / 256, 256, 0, stream>>>(Wusv, Wuvs, 2048, 5120, 32, NVU, NVU, wBu, 32 * 5120);

    hipMemsetAsync(agg, 0, (size_t)NN * 160 * sizeof(float), stream);
    msg_kernel<<<NE / 32, 256, 0, stream>>>(nf, ea, eidx, wAm, wBm, agg);
    upd_kernel<<<NN / 16, 256, 0, stream>>>(nf, agg, wAu, wBu, Wlms, Wlmv, Wlus, Wluv, out);
}